// Round 9
// baseline (114.408 us; speedup 1.0000x reference)
//
#include <hip/hip_runtime.h>

// feature_seq (B=2, C=64, N=512) fp32. Window lengths [256, 1024, 512, 512].
// Output i is (B, N, C, L_i), concatenated flat in d_out.
// out[b][n][c][l] = (0 <= n - L/2 + l < N) ? in[b][c][n - L/2 + l] : 0
//
// R9: fill-kernel-isomorphic structure. Each 64KB output block is a gather
// of <=16KB from the padded input, and within a block (b,n) are FIXED
// (only c varies): the block's output is linear in (row, window-elem). So:
// stage the 16KB slice into LDS (coalesced 4B-aligned vector loads from the
// zero-padded ws copy), barrier, then the hot loop is pure
// ds_read_b128 -> plain global_store_dwordx4 — NO global loads, no nt.
// This matches the 6.8 TB/s fillBuffer structure as closely as possible.

constexpr int B = 2;
constexpr int C = 64;   // log2 = 6
constexpr int N = 512;  // log2 = 9

constexpr int SZ256  = B * N * C * 256;   // 16,777,216 floats
constexpr int SZ1024 = B * N * C * 1024;  // 67,108,864
constexpr int SZ512  = B * N * C * 512;   // 33,554,432

constexpr int BLK256  = SZ256  / 4 / 1024;  // 4096 blocks
constexpr int BLK1024 = SZ1024 / 4 / 1024;  // 16384
constexpr int BLK512  = SZ512  / 4 / 1024;  // 8192
constexpr int NBLK = BLK256 + BLK1024 + 2 * BLK512;  // 36864

constexpr int PROW = 1536;  // padded row: [512 zeros | 512 data | 512 zeros]

typedef float f32x4 __attribute__((ext_vector_type(4)));
typedef float f32x4u __attribute__((ext_vector_type(4), aligned(4)));

// 128 rows; 384 threads = one float4 slot each (slots 128..255 hold data).
__global__ __launch_bounds__(384)
void pad_kernel(const float* __restrict__ in, float* __restrict__ ws) {
    const int row = blockIdx.x;   // (b<<6)|c, 0..127
    const int p = threadIdx.x;    // float4 slot 0..383
    f32x4 v = {0.0f, 0.0f, 0.0f, 0.0f};
    if (p >= 128 && p < 256)
        v = *reinterpret_cast<const f32x4*>(in + (row << 9) + ((p - 128) << 2));
    *reinterpret_cast<f32x4*>(ws + row * PROW + (p << 2)) = v;
}

template <int L>
__device__ __forceinline__ void do_seg(const float* __restrict__ ws,
                                       float* __restrict__ out,
                                       f32x4* __restrict__ lds,
                                       int blk, int tid) {
    constexpr int HALF = L / 2;
    constexpr int BIAS = 512 - HALF;      // padded offset of window start @n=0
    constexpr int L4 = L / 4;
    constexpr int L4_BITS = (L == 256) ? 6 : (L == 512) ? 7 : 8;

    // Block-uniform decode: all 1024 float4 of this block share (b, n);
    // rows are c0..c0+NR-1 where NR = 1024 >> L4_BITS.
    const int R0 = (blk * 1024) >> L4_BITS;
    const int c0 = R0 & (C - 1);
    const int n  = (R0 >> 6) & (N - 1);
    const int bb = R0 >> 15;
    const float* __restrict__ rowbase =
        ws + ((bb << 6) | c0) * PROW + (BIAS + n);

    // Stage: LDS slot s == output float4 slot s of this block.
    // slot s -> row (s >> L4_BITS), window elem ((s & (L4-1)) << 2).
#pragma unroll
    for (int i = 0; i < 4; ++i) {
        int s = i * 256 + tid;
        int row = s >> L4_BITS;
        int within = (s & (L4 - 1)) << 2;
        lds[s] = *reinterpret_cast<const f32x4u*>(rowbase + row * PROW + within);
    }
    __syncthreads();

    // Hot loop: pure LDS-read -> plain store stream.
    f32x4* __restrict__ out4 = reinterpret_cast<f32x4*>(out) + blk * 1024;
#pragma unroll
    for (int k = 0; k < 4; ++k) {
        int s = k * 256 + tid;
        out4[s] = lds[s];
    }
}

__global__ __launch_bounds__(256)
void msw_fused_kernel(const float* __restrict__ ws, float* __restrict__ out) {
    __shared__ f32x4 lds[1024];   // 16 KB
    const int blk = blockIdx.x;
    const int tid = threadIdx.x;

    if (blk < BLK256) {
        do_seg<256>(ws, out, lds, blk, tid);
    } else if (blk < BLK256 + BLK1024) {
        do_seg<1024>(ws, out + SZ256, lds, blk - BLK256, tid);
    } else if (blk < BLK256 + BLK1024 + BLK512) {
        do_seg<512>(ws, out + SZ256 + SZ1024, lds, blk - (BLK256 + BLK1024), tid);
    } else {
        do_seg<512>(ws, out + SZ256 + SZ1024 + SZ512, lds,
                    blk - (BLK256 + BLK1024 + BLK512), tid);
    }
}

extern "C" void kernel_launch(void* const* d_in, const int* in_sizes, int n_in,
                              void* d_out, int out_size, void* d_ws, size_t ws_size,
                              hipStream_t stream) {
    const float* in = (const float*)d_in[0];
    float* out = (float*)d_out;
    float* ws = (float*)d_ws;   // needs B*C*PROW*4 = 786 KB scratch

    pad_kernel<<<B * C, 384, 0, stream>>>(in, ws);
    msw_fused_kernel<<<NBLK, 256, 0, stream>>>(ws, out);
}